// Round 23
// baseline (20.943 us; speedup 1.0000x reference)
//
#include <hip/hip_runtime.h>
#include <math.h>

#define SD 39
#define BLOCK 512   // 8 waves/block: finer occupancy granularity than 1024

typedef _Float16 half8 __attribute__((ext_vector_type(8)));
typedef float f32x16 __attribute__((ext_vector_type(16)));
typedef float vf4 __attribute__((ext_vector_type(4)));

// ---- 32x32x16 MFMA formulation (R22, verified) ----
// batch col = lane&31 through all layers; C layout col=lane&31,
// row=(reg&3)+8*(reg>>2)+4*(lane>>5). Slot space (h=lane>>5, j=0..7);
// kappa(slot->k) baked identically into weight frags (prologue) and data
// repacks (chain). Biases ride spare K-slots via constant-1 data column.
#define NFRAG 20
#define DW_QPE (NFRAG * 256)
#define DW_TOT (DW_QPE + 4)        // 20.5 KB LDS

#define MFMA32(W, X, C) __builtin_amdgcn_mfma_f32_32x32x16_f16((W), (X), (C), 0, 0, 0)

// Full per-tile chain (L1..D3 + store). L1/L2 interleaved so c1a is folded
// into c2 before c1b exists: peak live ~68 VGPR even with the B-tile's 24
// raw regs in flight.
__device__ __forceinline__ void chain32(
    const half8* __restrict__ hws, const float* __restrict__ qpep,
    int lane, int h, int c,
    half8 xf0, half8 xf1, half8 xf2,
    long long R, float* __restrict__ out)
{
    f32x16 z;
    #pragma unroll
    for (int i = 0; i < 16; i++) z[i] = 0.0f;

    half8 hbias;
    #pragma unroll
    for (int j = 0; j < 8; j++) hbias[j] = (_Float16)0.0f;
    if (h == 0) hbias[0] = (_Float16)1.0f;

    // ---- L1 tile a (o1 0..31): frags 0..2 ----
    f32x16 c1 = z;
    c1 = MFMA32(hws[0 * 64 + lane], xf0, c1);
    c1 = MFMA32(hws[1 * 64 + lane], xf1, c1);
    c1 = MFMA32(hws[2 * 64 + lane], xf2, c1);
    half8 hb0, hb1;
    #pragma unroll
    for (int j = 0; j < 8; j++) {
        hb0[j] = (_Float16)fmaxf(c1[j],     0.0f);
        hb1[j] = (_Float16)fmaxf(c1[8 + j], 0.0f);
    }
    // ---- L2 partial: consume hb0,hb1 now (c1a regs die) ----
    f32x16 c2 = z;
    c2 = MFMA32(hws[6 * 64 + lane], hb0, c2);
    c2 = MFMA32(hws[7 * 64 + lane], hb1, c2);

    // ---- L1 tile b (o1 32..63): frags 3..5 (reuses c1 regs) ----
    c1 = z;
    c1 = MFMA32(hws[3 * 64 + lane], xf0, c1);
    c1 = MFMA32(hws[4 * 64 + lane], xf1, c1);
    c1 = MFMA32(hws[5 * 64 + lane], xf2, c1);
    half8 hb2, hb3;
    #pragma unroll
    for (int j = 0; j < 8; j++) {
        hb2[j] = (_Float16)fmaxf(c1[j],     0.0f);
        hb3[j] = (_Float16)fmaxf(c1[8 + j], 0.0f);
    }
    // ---- L2 rest ----
    c2 = MFMA32(hws[8 * 64 + lane],  hb2,   c2);
    c2 = MFMA32(hws[9 * 64 + lane],  hb3,   c2);
    c2 = MFMA32(hws[10 * 64 + lane], hbias, c2);

    half8 h30, h31;
    #pragma unroll
    for (int j = 0; j < 8; j++) {
        h30[j] = (_Float16)fmaxf(c2[j],     0.0f);
        h31[j] = (_Float16)fmaxf(c2[8 + j], 0.0f);
    }

    // ---- L3: 2 data steps + bias ----
    f32x16 e = z;
    e = MFMA32(hws[11 * 64 + lane], h30,   e);
    e = MFMA32(hws[12 * 64 + lane], h31,   e);
    e = MFMA32(hws[13 * 64 + lane], hbias, e);

    // ---- quantum: ev_i = prod_{j<=i} cos(tanh(e_j)*pi + qp[2j]) ----
    // (RZ cancels under Z-measure; CNOT chain -> bit i = b0^..^bi)
    float ev[4]; float cp = 1.0f;
    #pragma unroll
    for (int r = 0; r < 4; r++) {
        float ex = __expf(2.0f * e[r]);
        float t = 1.0f - 2.0f / (ex + 1.0f);      // tanh
        cp *= __cosf(fmaf(t, 3.14159265358979323846f, qpep[r]));
        ev[r] = cp;
    }
    half8 evf;
    #pragma unroll
    for (int j = 0; j < 8; j++) evf[j] = (_Float16)0.0f;
    if (h == 0) {
        evf[0] = (_Float16)ev[0]; evf[1] = (_Float16)ev[1];
        evf[2] = (_Float16)ev[2]; evf[3] = (_Float16)ev[3];
        evf[4] = (_Float16)1.0f;                  // db1 slot
    }

    // ---- D1: single MFMA ----
    f32x16 cd1 = MFMA32(hws[14 * 64 + lane], evf, z);
    half8 hd0, hd1;
    #pragma unroll
    for (int j = 0; j < 8; j++) {
        hd0[j] = (_Float16)fmaxf(cd1[j],     0.0f);
        hd1[j] = (_Float16)fmaxf(cd1[8 + j], 0.0f);
    }

    // ---- D2: 2 data steps + bias ----
    f32x16 cd2 = z;
    cd2 = MFMA32(hws[15 * 64 + lane], hd0,   cd2);
    cd2 = MFMA32(hws[16 * 64 + lane], hd1,   cd2);
    cd2 = MFMA32(hws[17 * 64 + lane], hbias, cd2);

    half8 hd3;
    #pragma unroll
    for (int j = 0; j < 8; j++) hd3[j] = (_Float16)fmaxf(cd2[j], 0.0f);

    // ---- D3: 1 data step + bias; dims 4h+0..3 in regs 0..3 ----
    f32x16 o = z;
    o = MFMA32(hws[18 * 64 + lane], hd3,   o);
    o = MFMA32(hws[19 * 64 + lane], hbias, o);

    float4* op = (float4*)(out + (R + c) * 8 + 4 * h);   // ONE store (vmcnt acct)
    *op = make_float4(o[0], o[1], o[2], o[3]);
}

#define CONV3(A0, A1, A2, A3, A4, A5, X0, X1, X2)                          \
    {                                                                      \
        X0[0]=(_Float16)A0[0]; X0[1]=(_Float16)A0[1];                      \
        X0[2]=(_Float16)A0[2]; X0[3]=(_Float16)A0[3];                      \
        X0[4]=(_Float16)A1[0]; X0[5]=(_Float16)A1[1];                      \
        X0[6]=(_Float16)A1[2]; X0[7]=(_Float16)A1[3];                      \
        X1[0]=(_Float16)A2[0]; X1[1]=(_Float16)A2[1];                      \
        X1[2]=(_Float16)A2[2]; X1[3]=(_Float16)A2[3];                      \
        X1[4]=(_Float16)A3[0]; X1[5]=(_Float16)A3[1];                      \
        X1[6]=(_Float16)A3[2]; X1[7]=(_Float16)A3[3];                      \
        X2[0]=(_Float16)A4[0]; X2[1]=(_Float16)A4[1];                      \
        X2[2]=(_Float16)A4[2]; X2[3]=(_Float16)A4[3];                      \
        X2[4]=(_Float16)A5[1]; X2[5]=(_Float16)A5[2];                      \
        X2[6]=(_Float16)A5[3]; X2[7]=(_Float16)1.0f;                       \
    }

__global__ __launch_bounds__(BLOCK)
__attribute__((amdgpu_waves_per_eu(4)))
void qnet_kernel(const float* __restrict__ state,
                 const float* __restrict__ ew1, const float* __restrict__ eb1,
                 const float* __restrict__ ew2, const float* __restrict__ eb2,
                 const float* __restrict__ ew3, const float* __restrict__ eb3,
                 const float* __restrict__ qp,
                 const float* __restrict__ dw1, const float* __restrict__ db1,
                 const float* __restrict__ dw2, const float* __restrict__ db2,
                 const float* __restrict__ dw3, const float* __restrict__ db3,
                 float* __restrict__ out, long long nrows)
{
    __shared__ __align__(16) float lf[DW_TOT];
    _Float16* wh = (_Float16*)lf;
    const int tid = threadIdx.x;

    // ---- fragment build (identical to R22, 20 iters/thread at BLOCK=512) ----
    for (int i = tid; i < NFRAG * 512; i += BLOCK) {
        int f = i >> 9, l = (i >> 3) & 63, j = i & 7;
        int h = l >> 5, m = l & 31;
        float v = 0.0f;
        if (f < 6) {                         // L1
            int mt = f / 3, s = f % 3;
            int o = mt * 32 + m, k = s * 16 + 8 * h + j;
            v = (k < SD) ? ew1[o * SD + k] : (k == SD ? eb1[o] : 0.0f);
        } else if (f < 11) {                 // L2
            int s = f - 6;
            if (s < 4) {
                int r = (s & 1) * 8 + j;
                int o1 = (r & 3) + 8 * (r >> 2) + 4 * h + 32 * (s >> 1);
                v = ew2[m * 64 + o1];
            } else v = (h == 0 && j == 0) ? eb2[m] : 0.0f;
        } else if (f < 14) {                 // L3
            int s = f - 11;
            if (s < 2) {
                int r = s * 8 + j;
                int o2 = (r & 3) + 8 * (r >> 2) + 4 * h;
                v = (m < 4) ? ew3[m * 32 + o2] : 0.0f;
            } else v = (h == 0 && j == 0 && m < 4) ? eb3[m] : 0.0f;
        } else if (f == 14) {                // D1
            v = (h == 0) ? (j < 4 ? dw1[m * 4 + j]
                                  : (j == 4 ? db1[m] : 0.0f)) : 0.0f;
        } else if (f < 18) {                 // D2
            int s = f - 15;
            if (s < 2) {
                int r = s * 8 + j;
                int k1 = (r & 3) + 8 * (r >> 2) + 4 * h;
                v = (m < 16) ? dw2[m * 32 + k1] : 0.0f;
            } else v = (h == 0 && j == 0 && m < 16) ? db2[m] : 0.0f;
        } else {                             // D3
            int s = f - 18;
            if (s == 0) {
                int k = (j & 3) + 8 * (j >> 2) + 4 * h;
                v = (m < 8) ? dw3[m * 16 + k] : 0.0f;
            } else v = (h == 0 && j == 0 && m < 8) ? db3[m] : 0.0f;
        }
        wh[i] = (_Float16)v;
    }
    for (int i = tid; i < 4; i += BLOCK) lf[DW_QPE + i] = qp[2 * i];
    __syncthreads();

    const int lane = tid & 63;
    const int h = lane >> 5, c = lane & 31;
    const long long gwave = (long long)blockIdx.x * (BLOCK / 64) + (tid >> 6);
    const long long RA = gwave * 64;                   // 64 rows (2 tiles)/wave
    if (RA >= nrows) return;
    const long long RB = RA + 32;

    const half8* hws = (const half8*)lf;
    const float* qpep = lf + DW_QPE;

    // ---- 2-tile pipeline: issue ALL 12 loads in one opaque asm block ----
    // (forced issue point; tail cols 32..38 loaded by ALL lanes -- always
    // in-bounds, h=1 slot weights are zero so values are don't-care).
    const float* spA  = state + (RA + c) * SD;
    const float* spAm = spA + 8 * h;
    const float* spB  = state + (RB + c) * SD;
    const float* spBm = spB + 8 * h;

    vf4 a0, a1, a2, a3, a4, a5, b0, b1, b2, b3, b4, b5;
    asm volatile(
        "global_load_dwordx4 %0, %12, off\n\t"
        "global_load_dwordx4 %1, %12, off offset:16\n\t"
        "global_load_dwordx4 %2, %12, off offset:64\n\t"
        "global_load_dwordx4 %3, %12, off offset:80\n\t"
        "global_load_dwordx4 %4, %13, off offset:128\n\t"
        "global_load_dwordx4 %5, %13, off offset:140\n\t"
        "global_load_dwordx4 %6, %14, off\n\t"
        "global_load_dwordx4 %7, %14, off offset:16\n\t"
        "global_load_dwordx4 %8, %14, off offset:64\n\t"
        "global_load_dwordx4 %9, %14, off offset:80\n\t"
        "global_load_dwordx4 %10, %15, off offset:128\n\t"
        "global_load_dwordx4 %11, %15, off offset:140"
        : "=&v"(a0), "=&v"(a1), "=&v"(a2), "=&v"(a3), "=&v"(a4), "=&v"(a5),
          "=&v"(b0), "=&v"(b1), "=&v"(b2), "=&v"(b3), "=&v"(b4), "=&v"(b5)
        : "v"(spAm), "v"(spA), "v"(spBm), "v"(spB));

    // release tile A (B's 6 loads remain in flight under A's whole chain)
    asm volatile("s_waitcnt vmcnt(6)"
        : "+v"(a0), "+v"(a1), "+v"(a2), "+v"(a3), "+v"(a4), "+v"(a5));

    half8 xf0, xf1, xf2;
    CONV3(a0, a1, a2, a3, a4, a5, xf0, xf1, xf2)
    chain32(hws, qpep, lane, h, c, xf0, xf1, xf2, RA, out);

    // release tile B (vmcnt(0): also drains A's store -- small, overlapped)
    asm volatile("s_waitcnt vmcnt(0)"
        : "+v"(b0), "+v"(b1), "+v"(b2), "+v"(b3), "+v"(b4), "+v"(b5));

    CONV3(b0, b1, b2, b3, b4, b5, xf0, xf1, xf2)
    chain32(hws, qpep, lane, h, c, xf0, xf1, xf2, RB, out);
}

extern "C" void kernel_launch(void* const* d_in, const int* in_sizes, int n_in,
                              void* d_out, int out_size, void* d_ws, size_t ws_size,
                              hipStream_t stream) {
    const float* state = (const float*)d_in[0];
    const float* ew1 = (const float*)d_in[1];
    const float* eb1 = (const float*)d_in[2];
    const float* ew2 = (const float*)d_in[3];
    const float* eb2 = (const float*)d_in[4];
    const float* ew3 = (const float*)d_in[5];
    const float* eb3 = (const float*)d_in[6];
    const float* qp  = (const float*)d_in[7];
    const float* dw1 = (const float*)d_in[8];
    const float* db1 = (const float*)d_in[9];
    const float* dw2 = (const float*)d_in[10];
    const float* db2 = (const float*)d_in[11];
    const float* dw3 = (const float*)d_in[12];
    const float* db3 = (const float*)d_in[13];
    float* out = (float*)d_out;

    const long long B = in_sizes[0] / SD;              // 262144
    // 4096 waves x 64 rows = 262144; 512 blocks x 8 waves.
    const long long waves = (B + 63) / 64;
    const int blocks = (int)((waves + (BLOCK / 64) - 1) / (BLOCK / 64));
    hipLaunchKernelGGL(qnet_kernel, dim3(blocks), dim3(BLOCK), 0, stream,
                       state, ew1, eb1, ew2, eb2, ew3, eb3, qp,
                       dw1, db1, dw2, db2, dw3, db3, out, B);
}

// Round 24
// 17.666 us; speedup vs baseline: 1.1855x; 1.1855x over previous
//
#include <hip/hip_runtime.h>
#include <math.h>

#define SD 39
#define BLOCK 1024   // 16 waves/block, 2 blocks/CU -> 8 waves/SIMD

typedef _Float16 half8 __attribute__((ext_vector_type(8)));
typedef float f32x16 __attribute__((ext_vector_type(16)));

// ---- 32x32x16 MFMA formulation (R22, verified) ----
// Tile = 32 batch rows; batch col = lane&31 through ALL layers (C layout:
// col=lane&31, row=(reg&3)+8*(reg>>2)+4*(lane>>5), dtype-independent).
// Slot space (h=lane>>5, j=0..7) = 16 K-slots; kappa (slot->k) is OUR choice,
// baked identically into weight frags (prologue) and data repacks (loop).
// Biases ride spare K-slots via a constant-1 data column.
#define NFRAG 20
#define DW_QPE (NFRAG * 256)       // dword offset of qp[0,2,4,6]
#define DW_TOT (DW_QPE + 4)        // 20.5 KB LDS

__global__ __launch_bounds__(BLOCK)
__attribute__((amdgpu_waves_per_eu(4)))
void qnet_kernel(const float* __restrict__ state,
                 const float* __restrict__ ew1, const float* __restrict__ eb1,
                 const float* __restrict__ ew2, const float* __restrict__ eb2,
                 const float* __restrict__ ew3, const float* __restrict__ eb3,
                 const float* __restrict__ qp,
                 const float* __restrict__ dw1, const float* __restrict__ db1,
                 const float* __restrict__ dw2, const float* __restrict__ db2,
                 const float* __restrict__ dw3, const float* __restrict__ db3,
                 float* __restrict__ out, long long nrows)
{
    __shared__ __align__(16) float lf[DW_TOT];
    _Float16* wh = (_Float16*)lf;
    const int tid = threadIdx.x;

    // ---- fragment build (10 iters/thread) ----
    for (int i = tid; i < NFRAG * 512; i += BLOCK) {
        int f = i >> 9, l = (i >> 3) & 63, j = i & 7;
        int h = l >> 5, m = l & 31;
        float v = 0.0f;
        if (f < 6) {                         // L1
            int mt = f / 3, s = f % 3;
            int o = mt * 32 + m, k = s * 16 + 8 * h + j;
            v = (k < SD) ? ew1[o * SD + k] : (k == SD ? eb1[o] : 0.0f);
        } else if (f < 11) {                 // L2
            int s = f - 6;
            if (s < 4) {
                int r = (s & 1) * 8 + j;
                int o1 = (r & 3) + 8 * (r >> 2) + 4 * h + 32 * (s >> 1);
                v = ew2[m * 64 + o1];
            } else v = (h == 0 && j == 0) ? eb2[m] : 0.0f;
        } else if (f < 14) {                 // L3
            int s = f - 11;
            if (s < 2) {
                int r = s * 8 + j;
                int o2 = (r & 3) + 8 * (r >> 2) + 4 * h;
                v = (m < 4) ? ew3[m * 32 + o2] : 0.0f;
            } else v = (h == 0 && j == 0 && m < 4) ? eb3[m] : 0.0f;
        } else if (f == 14) {                // D1
            v = (h == 0) ? (j < 4 ? dw1[m * 4 + j]
                                  : (j == 4 ? db1[m] : 0.0f)) : 0.0f;
        } else if (f < 18) {                 // D2
            int s = f - 15;
            if (s < 2) {
                int r = s * 8 + j;
                int k1 = (r & 3) + 8 * (r >> 2) + 4 * h;
                v = (m < 16) ? dw2[m * 32 + k1] : 0.0f;
            } else v = (h == 0 && j == 0 && m < 16) ? db2[m] : 0.0f;
        } else {                             // D3
            int s = f - 18;
            if (s == 0) {
                int k = (j & 3) + 8 * (j >> 2) + 4 * h;
                v = (m < 8) ? dw3[m * 16 + k] : 0.0f;
            } else v = (h == 0 && j == 0 && m < 8) ? db3[m] : 0.0f;
        }
        wh[i] = (_Float16)v;
    }
    for (int i = tid; i < 4; i += BLOCK) lf[DW_QPE + i] = qp[2 * i];
    __syncthreads();

    const int lane = tid & 63;
    const int h = lane >> 5, c = lane & 31;
    const long long gwave = (long long)blockIdx.x * (BLOCK / 64) + (tid >> 6);
    const long long R = gwave * 32;                    // 32 rows per wave
    if (R >= nrows) return;

    const half8* hws = (const half8*)lf;               // frag f: hws[f*64+lane]
    const float* qpep = lf + DW_QPE;

    // ---- state B-fragments: xf[s][j] = state[row=R+c][k = s*16+8h+j] ----
    const float* sp = state + (R + c) * SD;
    float4 r0 = *(const float4*)(sp + 8 * h);
    float4 r1 = *(const float4*)(sp + 8 * h + 4);
    float4 r2 = *(const float4*)(sp + 16 + 8 * h);
    float4 r3 = *(const float4*)(sp + 20 + 8 * h);
    float4 r4 = make_float4(0.f, 0.f, 0.f, 0.f);
    float4 r5 = make_float4(0.f, 0.f, 0.f, 0.f);
    if (h == 0) {                       // cols 32..38 (h=1 slots are k>=40 -> w=0)
        r4 = *(const float4*)(sp + 32);
        r5 = *(const float4*)(sp + 35); // ends exactly at col 38 (in-bounds)
    }
    half8 xf0, xf1, xf2;
    xf0[0]=(_Float16)r0.x; xf0[1]=(_Float16)r0.y; xf0[2]=(_Float16)r0.z; xf0[3]=(_Float16)r0.w;
    xf0[4]=(_Float16)r1.x; xf0[5]=(_Float16)r1.y; xf0[6]=(_Float16)r1.z; xf0[7]=(_Float16)r1.w;
    xf1[0]=(_Float16)r2.x; xf1[1]=(_Float16)r2.y; xf1[2]=(_Float16)r2.z; xf1[3]=(_Float16)r2.w;
    xf1[4]=(_Float16)r3.x; xf1[5]=(_Float16)r3.y; xf1[6]=(_Float16)r3.z; xf1[7]=(_Float16)r3.w;
    xf2[0]=(_Float16)r4.x; xf2[1]=(_Float16)r4.y; xf2[2]=(_Float16)r4.z; xf2[3]=(_Float16)r4.w;
    xf2[4]=(_Float16)r5.y; xf2[5]=(_Float16)r5.z; xf2[6]=(_Float16)r5.w;
    xf2[7]=(_Float16)1.0f;              // k=39 bias column (w=0 for h=1)

    f32x16 z;
    #pragma unroll
    for (int i = 0; i < 16; i++) z[i] = 0.0f;

    // Waves here are independent (no barriers) -> setprio around MFMA
    // clusters lets the CU scheduler favor the matrix-feeding wave (the
    // attn-style case where it measurably helps; null only in lockstep).
    __builtin_amdgcn_s_setprio(1);

    // ---- L1: two independent 32-row M-tiles, 3 K-steps ----
    f32x16 c1a = z, c1b = z;
    c1a = __builtin_amdgcn_mfma_f32_32x32x16_f16(hws[0*64+lane], xf0, c1a, 0,0,0);
    c1b = __builtin_amdgcn_mfma_f32_32x32x16_f16(hws[3*64+lane], xf0, c1b, 0,0,0);
    c1a = __builtin_amdgcn_mfma_f32_32x32x16_f16(hws[1*64+lane], xf1, c1a, 0,0,0);
    c1b = __builtin_amdgcn_mfma_f32_32x32x16_f16(hws[4*64+lane], xf1, c1b, 0,0,0);
    c1a = __builtin_amdgcn_mfma_f32_32x32x16_f16(hws[2*64+lane], xf2, c1a, 0,0,0);
    c1b = __builtin_amdgcn_mfma_f32_32x32x16_f16(hws[5*64+lane], xf2, c1b, 0,0,0);

    // relu + repack into L2 B-frags
    half8 hb0, hb1, hb2, hb3, hbias;
    #pragma unroll
    for (int j = 0; j < 8; j++) {
        hb0[j] = (_Float16)fmaxf(c1a[j],     0.0f);
        hb1[j] = (_Float16)fmaxf(c1a[8 + j], 0.0f);
        hb2[j] = (_Float16)fmaxf(c1b[j],     0.0f);
        hb3[j] = (_Float16)fmaxf(c1b[8 + j], 0.0f);
        hbias[j] = (_Float16)0.0f;
    }
    hbias[0] = (h == 0) ? (_Float16)1.0f : (_Float16)0.0f;

    // ---- L2: 4 data steps + bias step ----
    f32x16 c2 = z;
    c2 = __builtin_amdgcn_mfma_f32_32x32x16_f16(hws[6*64+lane],  hb0,  c2, 0,0,0);
    c2 = __builtin_amdgcn_mfma_f32_32x32x16_f16(hws[7*64+lane],  hb1,  c2, 0,0,0);
    c2 = __builtin_amdgcn_mfma_f32_32x32x16_f16(hws[8*64+lane],  hb2,  c2, 0,0,0);
    c2 = __builtin_amdgcn_mfma_f32_32x32x16_f16(hws[9*64+lane],  hb3,  c2, 0,0,0);
    c2 = __builtin_amdgcn_mfma_f32_32x32x16_f16(hws[10*64+lane], hbias, c2, 0,0,0);

    half8 h30, h31;
    #pragma unroll
    for (int j = 0; j < 8; j++) {
        h30[j] = (_Float16)fmaxf(c2[j],     0.0f);
        h31[j] = (_Float16)fmaxf(c2[8 + j], 0.0f);
    }

    // ---- L3: 2 data steps + bias ----
    f32x16 e = z;
    e = __builtin_amdgcn_mfma_f32_32x32x16_f16(hws[11*64+lane], h30,  e, 0,0,0);
    e = __builtin_amdgcn_mfma_f32_32x32x16_f16(hws[12*64+lane], h31,  e, 0,0,0);
    e = __builtin_amdgcn_mfma_f32_32x32x16_f16(hws[13*64+lane], hbias, e, 0,0,0);

    __builtin_amdgcn_s_setprio(0);      // transcendental block: plain priority

    // ---- quantum: ev_i = prod_{j<=i} cos(tanh(e_j)*pi + qp[2j]) ----
    // (RZ cancels under Z-measure; CNOT chain -> bit i = b0^..^bi)
    float ev[4]; float cp = 1.0f;
    #pragma unroll
    for (int r = 0; r < 4; r++) {
        float ex = __expf(2.0f * e[r]);
        float t = 1.0f - 2.0f / (ex + 1.0f);      // tanh
        cp *= __cosf(fmaf(t, 3.14159265358979323846f, qpep[r]));
        ev[r] = cp;
    }
    half8 evf;
    #pragma unroll
    for (int j = 0; j < 8; j++) evf[j] = (_Float16)0.0f;
    if (h == 0) {
        evf[0] = (_Float16)ev[0]; evf[1] = (_Float16)ev[1];
        evf[2] = (_Float16)ev[2]; evf[3] = (_Float16)ev[3];
        evf[4] = (_Float16)1.0f;                  // db1 slot
    }

    __builtin_amdgcn_s_setprio(1);      // decoder MFMA cluster

    // ---- D1: single MFMA (K-slots 0..4 of h==0) ----
    f32x16 cd1 = __builtin_amdgcn_mfma_f32_32x32x16_f16(hws[14*64+lane], evf, z, 0,0,0);
    half8 hd0, hd1;
    #pragma unroll
    for (int j = 0; j < 8; j++) {
        hd0[j] = (_Float16)fmaxf(cd1[j],     0.0f);
        hd1[j] = (_Float16)fmaxf(cd1[8 + j], 0.0f);
    }

    // ---- D2: 2 data steps + bias ----
    f32x16 cd2 = z;
    cd2 = __builtin_amdgcn_mfma_f32_32x32x16_f16(hws[15*64+lane], hd0,  cd2, 0,0,0);
    cd2 = __builtin_amdgcn_mfma_f32_32x32x16_f16(hws[16*64+lane], hd1,  cd2, 0,0,0);
    cd2 = __builtin_amdgcn_mfma_f32_32x32x16_f16(hws[17*64+lane], hbias, cd2, 0,0,0);

    half8 hd3;
    #pragma unroll
    for (int j = 0; j < 8; j++) hd3[j] = (_Float16)fmaxf(cd2[j], 0.0f);

    // ---- D3: 1 data step + bias; rows 0..7 -> regs 0..3 at dims 4h+0..3 ----
    f32x16 o = z;
    o = __builtin_amdgcn_mfma_f32_32x32x16_f16(hws[18*64+lane], hd3,  o, 0,0,0);
    o = __builtin_amdgcn_mfma_f32_32x32x16_f16(hws[19*64+lane], hbias, o, 0,0,0);

    __builtin_amdgcn_s_setprio(0);

    float4* op = (float4*)(out + (R + c) * 8 + 4 * h);   // full-wave store
    *op = make_float4(o[0], o[1], o[2], o[3]);
}

extern "C" void kernel_launch(void* const* d_in, const int* in_sizes, int n_in,
                              void* d_out, int out_size, void* d_ws, size_t ws_size,
                              hipStream_t stream) {
    const float* state = (const float*)d_in[0];
    const float* ew1 = (const float*)d_in[1];
    const float* eb1 = (const float*)d_in[2];
    const float* ew2 = (const float*)d_in[3];
    const float* eb2 = (const float*)d_in[4];
    const float* ew3 = (const float*)d_in[5];
    const float* eb3 = (const float*)d_in[6];
    const float* qp  = (const float*)d_in[7];
    const float* dw1 = (const float*)d_in[8];
    const float* db1 = (const float*)d_in[9];
    const float* dw2 = (const float*)d_in[10];
    const float* db2 = (const float*)d_in[11];
    const float* dw3 = (const float*)d_in[12];
    const float* db3 = (const float*)d_in[13];
    float* out = (float*)d_out;

    const long long B = in_sizes[0] / SD;              // 262144
    // 8192 waves x 32 rows = 262144; 512 blocks x 16 waves, 2 blocks/CU.
    const int blocks = (int)((B / 32 + (BLOCK / 64) - 1) / (BLOCK / 64));
    hipLaunchKernelGGL(qnet_kernel, dim3(blocks), dim3(BLOCK), 0, stream,
                       state, ew1, eb1, ew2, eb2, ew3, eb3, qp,
                       dw1, db1, dw2, db2, dw3, db3, out, B);
}

// Round 25
// 16.973 us; speedup vs baseline: 1.2340x; 1.0409x over previous
//
#include <hip/hip_runtime.h>
#include <math.h>

#define SD 39
#define BLOCK 1024   // 16 waves/block, 2 blocks/CU -> 32 waves/CU = 8/SIMD

typedef _Float16 half8 __attribute__((ext_vector_type(8)));
typedef float f32x16 __attribute__((ext_vector_type(16)));

// ---- 32x32x16 MFMA formulation (R22, verified) ----
// Tile = 32 batch rows; batch col = lane&31 through ALL layers (C layout:
// col=lane&31, row=(reg&3)+8*(reg>>2)+4*(lane>>5), dtype-independent).
// Slot space (h=lane>>5, j=0..7); kappa(slot->k) baked identically into
// weight frags (prologue) and data repacks (chain). Biases ride spare
// K-slots via a constant-1 data column.
// CHAIN ORDER (R25): c1a is folded into c2 BEFORE c1b is computed -- peak
// live regs ~60 (was ~85) so the kernel fits the 64-VGPR / 8-waves-per-SIMD
// allocation demanded by amdgpu_waves_per_eu(8).
#define NFRAG 20
#define DW_QPE (NFRAG * 256)       // dword offset of qp[0,2,4,6]
#define DW_TOT (DW_QPE + 4)        // 20.5 KB LDS

#define MFMA32(W, X, C) __builtin_amdgcn_mfma_f32_32x32x16_f16((W), (X), (C), 0, 0, 0)

__global__ __launch_bounds__(BLOCK)
__attribute__((amdgpu_waves_per_eu(8)))   // demand VGPR<=64 -> 8 waves/SIMD
void qnet_kernel(const float* __restrict__ state,
                 const float* __restrict__ ew1, const float* __restrict__ eb1,
                 const float* __restrict__ ew2, const float* __restrict__ eb2,
                 const float* __restrict__ ew3, const float* __restrict__ eb3,
                 const float* __restrict__ qp,
                 const float* __restrict__ dw1, const float* __restrict__ db1,
                 const float* __restrict__ dw2, const float* __restrict__ db2,
                 const float* __restrict__ dw3, const float* __restrict__ db3,
                 float* __restrict__ out, long long nrows)
{
    __shared__ __align__(16) float lf[DW_TOT];
    _Float16* wh = (_Float16*)lf;
    const int tid = threadIdx.x;

    // ---- fragment build (10 iters/thread; identical to R22) ----
    for (int i = tid; i < NFRAG * 512; i += BLOCK) {
        int f = i >> 9, l = (i >> 3) & 63, j = i & 7;
        int h = l >> 5, m = l & 31;
        float v = 0.0f;
        if (f < 6) {                         // L1
            int mt = f / 3, s = f % 3;
            int o = mt * 32 + m, k = s * 16 + 8 * h + j;
            v = (k < SD) ? ew1[o * SD + k] : (k == SD ? eb1[o] : 0.0f);
        } else if (f < 11) {                 // L2
            int s = f - 6;
            if (s < 4) {
                int r = (s & 1) * 8 + j;
                int o1 = (r & 3) + 8 * (r >> 2) + 4 * h + 32 * (s >> 1);
                v = ew2[m * 64 + o1];
            } else v = (h == 0 && j == 0) ? eb2[m] : 0.0f;
        } else if (f < 14) {                 // L3
            int s = f - 11;
            if (s < 2) {
                int r = s * 8 + j;
                int o2 = (r & 3) + 8 * (r >> 2) + 4 * h;
                v = (m < 4) ? ew3[m * 32 + o2] : 0.0f;
            } else v = (h == 0 && j == 0 && m < 4) ? eb3[m] : 0.0f;
        } else if (f == 14) {                // D1
            v = (h == 0) ? (j < 4 ? dw1[m * 4 + j]
                                  : (j == 4 ? db1[m] : 0.0f)) : 0.0f;
        } else if (f < 18) {                 // D2
            int s = f - 15;
            if (s < 2) {
                int r = s * 8 + j;
                int k1 = (r & 3) + 8 * (r >> 2) + 4 * h;
                v = (m < 16) ? dw2[m * 32 + k1] : 0.0f;
            } else v = (h == 0 && j == 0 && m < 16) ? db2[m] : 0.0f;
        } else {                             // D3
            int s = f - 18;
            if (s == 0) {
                int k = (j & 3) + 8 * (j >> 2) + 4 * h;
                v = (m < 8) ? dw3[m * 16 + k] : 0.0f;
            } else v = (h == 0 && j == 0 && m < 8) ? db3[m] : 0.0f;
        }
        wh[i] = (_Float16)v;
    }
    for (int i = tid; i < 4; i += BLOCK) lf[DW_QPE + i] = qp[2 * i];
    __syncthreads();

    const int lane = tid & 63;
    const int h = lane >> 5, c = lane & 31;
    const long long gwave = (long long)blockIdx.x * (BLOCK / 64) + (tid >> 6);
    const long long R = gwave * 32;                    // 32 rows per wave
    if (R >= nrows) return;

    const half8* hws = (const half8*)lf;               // frag f: hws[f*64+lane]
    const float* qpep = lf + DW_QPE;

    // ---- state B-fragments: xf[s][j] = state[row=R+c][k = s*16+8h+j] ----
    const float* sp = state + (R + c) * SD;
    float4 r0 = *(const float4*)(sp + 8 * h);
    float4 r1 = *(const float4*)(sp + 8 * h + 4);
    float4 r2 = *(const float4*)(sp + 16 + 8 * h);
    float4 r3 = *(const float4*)(sp + 20 + 8 * h);
    float4 r4 = make_float4(0.f, 0.f, 0.f, 0.f);
    float4 r5 = make_float4(0.f, 0.f, 0.f, 0.f);
    if (h == 0) {                       // cols 32..38 (h=1 slots are k>=40 -> w=0)
        r4 = *(const float4*)(sp + 32);
        r5 = *(const float4*)(sp + 35); // ends exactly at col 38 (in-bounds)
    }
    half8 xf0, xf1, xf2;
    xf0[0]=(_Float16)r0.x; xf0[1]=(_Float16)r0.y; xf0[2]=(_Float16)r0.z; xf0[3]=(_Float16)r0.w;
    xf0[4]=(_Float16)r1.x; xf0[5]=(_Float16)r1.y; xf0[6]=(_Float16)r1.z; xf0[7]=(_Float16)r1.w;
    xf1[0]=(_Float16)r2.x; xf1[1]=(_Float16)r2.y; xf1[2]=(_Float16)r2.z; xf1[3]=(_Float16)r2.w;
    xf1[4]=(_Float16)r3.x; xf1[5]=(_Float16)r3.y; xf1[6]=(_Float16)r3.z; xf1[7]=(_Float16)r3.w;
    xf2[0]=(_Float16)r4.x; xf2[1]=(_Float16)r4.y; xf2[2]=(_Float16)r4.z; xf2[3]=(_Float16)r4.w;
    xf2[4]=(_Float16)r5.y; xf2[5]=(_Float16)r5.z; xf2[6]=(_Float16)r5.w;
    xf2[7]=(_Float16)1.0f;              // k=39 bias column (w=0 for h=1)

    f32x16 z;
    #pragma unroll
    for (int i = 0; i < 16; i++) z[i] = 0.0f;

    half8 hbias;
    #pragma unroll
    for (int j = 0; j < 8; j++) hbias[j] = (_Float16)0.0f;
    if (h == 0) hbias[0] = (_Float16)1.0f;

    // ---- L1 tile a (o1 0..31): frags 0..2; fold into c2 IMMEDIATELY so
    //      c1's 16 accumulator regs die before tile b is computed ----
    f32x16 c1 = z;
    c1 = MFMA32(hws[0 * 64 + lane], xf0, c1);
    c1 = MFMA32(hws[1 * 64 + lane], xf1, c1);
    c1 = MFMA32(hws[2 * 64 + lane], xf2, c1);
    half8 hb0, hb1;
    #pragma unroll
    for (int j = 0; j < 8; j++) {
        hb0[j] = (_Float16)fmaxf(c1[j],     0.0f);
        hb1[j] = (_Float16)fmaxf(c1[8 + j], 0.0f);
    }
    f32x16 c2 = z;
    c2 = MFMA32(hws[6 * 64 + lane], hb0, c2);
    c2 = MFMA32(hws[7 * 64 + lane], hb1, c2);

    // ---- L1 tile b (o1 32..63): frags 3..5 (c1 regs reused) ----
    c1 = z;
    c1 = MFMA32(hws[3 * 64 + lane], xf0, c1);
    c1 = MFMA32(hws[4 * 64 + lane], xf1, c1);
    c1 = MFMA32(hws[5 * 64 + lane], xf2, c1);
    #pragma unroll
    for (int j = 0; j < 8; j++) {
        hb0[j] = (_Float16)fmaxf(c1[j],     0.0f);
        hb1[j] = (_Float16)fmaxf(c1[8 + j], 0.0f);
    }
    c2 = MFMA32(hws[8 * 64 + lane],  hb0,   c2);
    c2 = MFMA32(hws[9 * 64 + lane],  hb1,   c2);
    c2 = MFMA32(hws[10 * 64 + lane], hbias, c2);

    half8 h30, h31;
    #pragma unroll
    for (int j = 0; j < 8; j++) {
        h30[j] = (_Float16)fmaxf(c2[j],     0.0f);
        h31[j] = (_Float16)fmaxf(c2[8 + j], 0.0f);
    }

    // ---- L3: 2 data steps + bias ----
    f32x16 e = z;
    e = MFMA32(hws[11 * 64 + lane], h30,   e);
    e = MFMA32(hws[12 * 64 + lane], h31,   e);
    e = MFMA32(hws[13 * 64 + lane], hbias, e);

    // ---- quantum: ev_i = prod_{j<=i} cos(tanh(e_j)*pi + qp[2j]) ----
    // (RZ cancels under Z-measure; CNOT chain -> bit i = b0^..^bi)
    float ev[4]; float cp = 1.0f;
    #pragma unroll
    for (int r = 0; r < 4; r++) {
        float ex = __expf(2.0f * e[r]);
        float t = 1.0f - 2.0f / (ex + 1.0f);      // tanh
        cp *= __cosf(fmaf(t, 3.14159265358979323846f, qpep[r]));
        ev[r] = cp;
    }
    half8 evf;
    #pragma unroll
    for (int j = 0; j < 8; j++) evf[j] = (_Float16)0.0f;
    if (h == 0) {
        evf[0] = (_Float16)ev[0]; evf[1] = (_Float16)ev[1];
        evf[2] = (_Float16)ev[2]; evf[3] = (_Float16)ev[3];
        evf[4] = (_Float16)1.0f;                  // db1 slot
    }

    // ---- D1: single MFMA (K-slots 0..4 of h==0) ----
    f32x16 cd1 = MFMA32(hws[14 * 64 + lane], evf, z);
    half8 hd0, hd1;
    #pragma unroll
    for (int j = 0; j < 8; j++) {
        hd0[j] = (_Float16)fmaxf(cd1[j],     0.0f);
        hd1[j] = (_Float16)fmaxf(cd1[8 + j], 0.0f);
    }

    // ---- D2: 2 data steps + bias ----
    f32x16 cd2 = z;
    cd2 = MFMA32(hws[15 * 64 + lane], hd0,   cd2);
    cd2 = MFMA32(hws[16 * 64 + lane], hd1,   cd2);
    cd2 = MFMA32(hws[17 * 64 + lane], hbias, cd2);

    half8 hd3;
    #pragma unroll
    for (int j = 0; j < 8; j++) hd3[j] = (_Float16)fmaxf(cd2[j], 0.0f);

    // ---- D3: 1 data step + bias; rows 0..7 -> regs 0..3 at dims 4h+0..3 ----
    f32x16 o = z;
    o = MFMA32(hws[18 * 64 + lane], hd3,   o);
    o = MFMA32(hws[19 * 64 + lane], hbias, o);

    float4* op = (float4*)(out + (R + c) * 8 + 4 * h);   // full-wave store
    *op = make_float4(o[0], o[1], o[2], o[3]);
}

extern "C" void kernel_launch(void* const* d_in, const int* in_sizes, int n_in,
                              void* d_out, int out_size, void* d_ws, size_t ws_size,
                              hipStream_t stream) {
    const float* state = (const float*)d_in[0];
    const float* ew1 = (const float*)d_in[1];
    const float* eb1 = (const float*)d_in[2];
    const float* ew2 = (const float*)d_in[3];
    const float* eb2 = (const float*)d_in[4];
    const float* ew3 = (const float*)d_in[5];
    const float* eb3 = (const float*)d_in[6];
    const float* qp  = (const float*)d_in[7];
    const float* dw1 = (const float*)d_in[8];
    const float* db1 = (const float*)d_in[9];
    const float* dw2 = (const float*)d_in[10];
    const float* db2 = (const float*)d_in[11];
    const float* dw3 = (const float*)d_in[12];
    const float* db3 = (const float*)d_in[13];
    float* out = (float*)d_out;

    const long long B = in_sizes[0] / SD;              // 262144
    // 8192 waves x 32 rows = 262144; 512 blocks x 16 waves, 2 blocks/CU.
    const int blocks = (int)((B / 32 + (BLOCK / 64) - 1) / (BLOCK / 64));
    hipLaunchKernelGGL(qnet_kernel, dim3(blocks), dim3(BLOCK), 0, stream,
                       state, ew1, eb1, ew2, eb2, ew3, eb3, qp,
                       dw1, db1, dw2, db2, dw3, db3, out, B);
}